// Round 5
// baseline (805.362 us; speedup 1.0000x reference)
//
#include <hip/hip_runtime.h>
#include <hip/hip_fp16.h>
#include <math.h>

#define NB 16
#define NA 720
#define ND 1024
#define NH 512
#define NW 512

#define TW 64      // tile width  (x)
#define TH 16      // tile height (y)
#define PXT 4      // y-pixels per thread
#define WINN 96    // detector window entries per batch (span <= 67 for 64x16 tile)

__device__ __forceinline__ uint32_t h2_to_u32(__half2 h) {
    union { __half2 h; uint32_t u; } v; v.h = h; return v.u;
}
__device__ __forceinline__ __half2 u32_to_h2(uint32_t u) {
    union { __half2 h; uint32_t u; } v; v.u = u; return v.h;
}

// ---------------------------------------------------------------------------
// Kernel 0: per-angle cos/sin table (matches jnp.linspace(0, pi, A, endpoint=False))
// ---------------------------------------------------------------------------
__global__ __launch_bounds__(256) void angle_kernel(float2* __restrict__ cs) {
    int a = blockIdx.x * 256 + threadIdx.x;
    if (a < NA) {
        const float step = (float)(M_PI / (double)NA);
        float ang = (float)a * step;
        float s, c;
        sincosf(ang, &s, &c);
        cs[a] = make_float2(c, s);
    }
}

// ---------------------------------------------------------------------------
// Kernel 1: ramp filter via in-LDS Stockham radix-2 FFT (fp32), TWO real rows
// per block packed as z = x0 + i*x1. Filter is real & even-symmetric, so
// Y = filt*Z directly; IFFT gives y0 = Re, y1 = Im. 1/ND ifft-norm folded in
// (pi/NA applied at backproj epilogue to keep fp16 staging well-scaled).
// ---------------------------------------------------------------------------
__global__ __launch_bounds__(256) void filter_kernel(const float* __restrict__ sino,
                                                     const float* __restrict__ filt,
                                                     float* __restrict__ outp) {
    __shared__ float2 bufA[ND];
    __shared__ float2 bufB[ND];
    __shared__ float2 tw[ND / 2];   // tw[m] = exp(-2*pi*i*m/ND)

    const int tid = threadIdx.x;
    const size_t r0 = (size_t)blockIdx.x * 2;
    const float* __restrict__ xa = sino + r0 * ND;
    const float* __restrict__ xb = xa + ND;
    float* __restrict__ ya = outp + r0 * ND;
    float* __restrict__ yb = ya + ND;

    #pragma unroll
    for (int i = 0; i < ND; i += 256)
        bufA[i + tid] = make_float2(xa[i + tid], xb[i + tid]);
    #pragma unroll
    for (int i = 0; i < ND / 2; i += 256) {
        int m = i + tid;
        float ang = (float)(-2.0 * M_PI / (double)ND) * (float)m;
        float s, c;
        sincosf(ang, &s, &c);
        tw[m] = make_float2(c, s);
    }
    __syncthreads();

    float2* src = bufA;
    float2* dst = bufB;

    // forward FFT: Stockham, Ns = 1..512
    for (int Ns = 1; Ns < ND; Ns <<= 1) {
        #pragma unroll
        for (int q = 0; q < ND / 2; q += 256) {
            int j = q + tid;
            int m = j & (Ns - 1);
            float2 v0 = src[j];
            float2 v1 = src[j + ND / 2];
            float2 w = tw[m * (ND / 2 / Ns)];
            float tr = w.x * v1.x - w.y * v1.y;
            float ti = w.x * v1.y + w.y * v1.x;
            int d = ((j & ~(Ns - 1)) << 1) + m;
            dst[d]      = make_float2(v0.x + tr, v0.y + ti);
            dst[d + Ns] = make_float2(v0.x - tr, v0.y - ti);
        }
        __syncthreads();
        float2* tmp = src; src = dst; dst = tmp;
    }

    // multiply by real filter, with 1/ND folded in
    const float SCALE = 1.0f / (float)ND;
    #pragma unroll
    for (int i = 0; i < ND; i += 256) {
        float f = filt[i + tid] * SCALE;
        src[i + tid].x *= f;
        src[i + tid].y *= f;
    }
    __syncthreads();

    // inverse FFT: same flow with conjugated twiddles
    for (int Ns = 1; Ns < ND; Ns <<= 1) {
        #pragma unroll
        for (int q = 0; q < ND / 2; q += 256) {
            int j = q + tid;
            int m = j & (Ns - 1);
            float2 v0 = src[j];
            float2 v1 = src[j + ND / 2];
            float2 w = tw[m * (ND / 2 / Ns)];
            float tr = w.x * v1.x + w.y * v1.y;   // conj(w)*v1
            float ti = w.x * v1.y - w.y * v1.x;
            int d = ((j & ~(Ns - 1)) << 1) + m;
            dst[d]      = make_float2(v0.x + tr, v0.y + ti);
            dst[d + Ns] = make_float2(v0.x - tr, v0.y - ti);
        }
        __syncthreads();
        float2* tmp = src; src = dst; dst = tmp;
    }

    #pragma unroll
    for (int i = 0; i < ND; i += 256) {
        ya[i + tid] = src[i + tid].x;   // row r0   (Re)
        yb[i + tid] = src[i + tid].y;   // row r0+1 (Im)
    }
}

// ---------------------------------------------------------------------------
// Kernel 2: backprojection. 64x16 pixel tile x 2 BATCHES per 256-thread block.
// Window entry i is 8B: (h(f_b0[i]), h(df_b0[i]), h(f_b1[i]), h(df_b1[i]))
// -> ONE ds_read_b64 serves BOTH batches' lerps (DS pipe was the R4 bound).
// Per-angle (c,s) comes from a wave-uniform s_load (SMEM, not DS); the window
// base is recomputed per thread (~9 VALU, block-uniform arithmetic).
// Bounds check eliminated: |px*c+py*s| <= 361.3 < 511.5 always in-range;
// local index i0 in [1, 67] subset of [0, WINN-2].
// ---------------------------------------------------------------------------
__global__ __launch_bounds__(256, 8) void backproj_kernel(const float* __restrict__ filtered,
                                                          const float2* __restrict__ cs_tab,
                                                          float* __restrict__ img) {
    __shared__ __align__(16) uint32_t win[2][2 * WINN];   // 1.5 KB

    const int tid = threadIdx.x;
    const int bx = blockIdx.x, by = blockIdx.y, bz = blockIdx.z;

    const float x0 = (float)(bx * TW) - 255.5f;
    const float x1 = x0 + (float)(TW - 1);
    const float y0 = (float)(by * TH) - 255.5f;

    // per-angle params, block-uniform: (c, s, 511.5-base, bits(a*ND+base))
    // s >= 0 for angles in [0, pi) -> min over y at y0.
    auto calc_params = [&](int a) -> float4 {
        float2 cs = cs_tab[a];           // uniform address -> s_load_dwordx2
        float tmin = 511.5f + fminf(x0 * cs.x, x1 * cs.x) + y0 * cs.y;
        int base = (int)floorf(tmin) - 1;
        return make_float4(cs.x, cs.y, 511.5f - (float)base,
                           __int_as_float(a * ND + base));
    };

    // staging: threads 0..95 -> batch0, 96..191 -> batch1 (word g of entry si)
    const bool stg = tid < 2 * WINN;
    const int g    = (tid >= WINN) ? 1 : 0;
    const int si   = tid - g * WINN;
    const float* __restrict__ srow =
        filtered + (size_t)(bz * 2 + g) * NA * ND + si;

    const int tx  = tid & (TW - 1);
    const int ty0 = (tid / TW) * PXT;
    const float px  = (float)(bx * TW + tx)  - 255.5f;
    const float pyf = (float)(by * TH + ty0) - 255.5f;

    float acc0[PXT], acc1[PXT];
    #pragma unroll
    for (int k = 0; k < PXT; k++) { acc0[k] = 0.0f; acc1[k] = 0.0f; }

    // prologue: stage angle 0 into phase 0
    float4 P = calc_params(0);
    if (stg) {
        int soff = __float_as_int(P.w);
        float f0 = srow[soff], f1 = srow[soff + 1];
        win[0][2 * si + g] =
            h2_to_u32(__halves2half2(__float2half_rn(f0), __float2half_rn(f1 - f0)));
    }
    __syncthreads();

    for (int a0 = 0; a0 < NA; a0 += 2) {
        #pragma unroll
        for (int p = 0; p < 2; p++) {
            const int a = a0 + p;
            float4 Pn = P;
            uint32_t stage_val = 0;
            const bool pre = (a + 1 < NA);
            if (pre) {
                Pn = calc_params(a + 1);
                if (stg) {
                    int soff = __float_as_int(Pn.w);
                    float f0 = srow[soff], f1 = srow[soff + 1];
                    stage_val = h2_to_u32(
                        __halves2half2(__float2half_rn(f0), __float2half_rn(f1 - f0)));
                }
            }

            const float sy = P.y;
            const float tb = fmaf(px, P.x, fmaf(pyf, sy, P.z));
            #pragma unroll
            for (int k = 0; k < PXT; k++) {
                float t  = fmaf((float)k, sy, tb);
                int   i0 = (int)t;                       // t > 0 -> trunc == floor
#if __has_builtin(__builtin_amdgcn_fractf)
                float w  = __builtin_amdgcn_fractf(t);
#else
                float w  = t - (float)i0;
#endif
                const uint2 pk = *(const uint2*)&win[p][2 * i0];   // ds_read_b64
                float2 fd0 = __half22float2(u32_to_h2(pk.x));      // batch0 (f, df)
                float2 fd1 = __half22float2(u32_to_h2(pk.y));      // batch1 (f, df)
                acc0[k] = fmaf(w, fd0.y, acc0[k] + fd0.x);
                acc1[k] = fmaf(w, fd1.y, acc1[k] + fd1.x);
            }

            if (pre && stg)
                win[p ^ 1][2 * si + g] = stage_val;
            P = Pn;
            __syncthreads();
        }
    }

    const float SCALE = (float)(M_PI / (double)NA);
    size_t o0 = (((size_t)(bz * 2) * NH) + (by * TH + ty0)) * NW + (bx * TW + tx);
    size_t o1 = o0 + (size_t)NH * NW;
    #pragma unroll
    for (int k = 0; k < PXT; k++) {
        img[o0 + (size_t)k * NW] = acc0[k] * SCALE;
        img[o1 + (size_t)k * NW] = acc1[k] * SCALE;
    }
}

// ---------------------------------------------------------------------------
extern "C" void kernel_launch(void* const* d_in, const int* in_sizes, int n_in,
                              void* d_out, int out_size, void* d_ws, size_t ws_size,
                              hipStream_t stream) {
    const float* sino = (const float*)d_in[0];
    const float* filt = (const float*)d_in[1];
    float* out = (float*)d_out;

    const size_t filt_bytes = (size_t)NB * NA * ND * sizeof(float);
    float* filtered;
    float2* cs_tab;
    if (ws_size >= filt_bytes + 4096) {
        filtered = (float*)d_ws;
        cs_tab = (float2*)((char*)d_ws + filt_bytes);
    } else {
        // fallback: filter in-place into the input (harness restores inputs
        // from a pristine copy before every launch)
        filtered = (float*)d_in[0];
        cs_tab = (float2*)d_ws;
    }

    angle_kernel<<<dim3(3), dim3(256), 0, stream>>>(cs_tab);
    filter_kernel<<<dim3(NB * NA / 2), dim3(256), 0, stream>>>(sino, filt, filtered);
    backproj_kernel<<<dim3(NW / TW, NH / TH, NB / 2), dim3(256), 0, stream>>>(filtered, cs_tab, out);
}

// Round 7
// 684.510 us; speedup vs baseline: 1.1766x; 1.1766x over previous
//
#include <hip/hip_runtime.h>
#include <hip/hip_fp16.h>
#include <math.h>

#define NB 16
#define NA 720
#define ND 1024
#define NH 512
#define NW 512

#define TW 64      // tile width  (x)
#define TH 16      // tile height (y)
#define PXT 4      // y-pixels per thread
#define WINN 96    // detector window entries per batch (span <= 67 for 64x16 tile)
#define GROUP 16   // angles per fp16-accumulate group (720 = 45*16)

typedef __fp16 h2vec __attribute__((ext_vector_type(2)));

__device__ __forceinline__ uint32_t pkrtz_u32(float a, float b) {
    union { h2vec h; uint32_t u; } v;
    v.h = __builtin_amdgcn_cvt_pkrtz(a, b);   // one v_cvt_pkrtz_f16_f32
    return v.u;
}
__device__ __forceinline__ __half2 u32_to_h2(uint32_t u) {
    union { uint32_t u; __half2 h; } v; v.u = u; return v.h;
}

// ---------------------------------------------------------------------------
// Kernel 0: per-angle cos/sin table (matches jnp.linspace(0, pi, A, endpoint=False))
// ---------------------------------------------------------------------------
__global__ __launch_bounds__(256) void angle_kernel(float2* __restrict__ cs) {
    int a = blockIdx.x * 256 + threadIdx.x;
    if (a < NA) {
        const float step = (float)(M_PI / (double)NA);
        float ang = (float)a * step;
        float s, c;
        sincosf(ang, &s, &c);
        cs[a] = make_float2(c, s);
    }
}

// ---------------------------------------------------------------------------
// Kernel 1: ramp filter via in-LDS Stockham radix-2 FFT (fp32), TWO real rows
// per block packed as z = x0 + i*x1. Filter is real & even-symmetric, so
// Y = filt*Z directly; IFFT gives y0 = Re, y1 = Im. 1/ND ifft-norm folded in
// (pi/NA applied at backproj epilogue to keep fp16 staging well-scaled).
// ---------------------------------------------------------------------------
__global__ __launch_bounds__(256) void filter_kernel(const float* __restrict__ sino,
                                                     const float* __restrict__ filt,
                                                     float* __restrict__ outp) {
    __shared__ float2 bufA[ND];
    __shared__ float2 bufB[ND];
    __shared__ float2 tw[ND / 2];   // tw[m] = exp(-2*pi*i*m/ND)

    const int tid = threadIdx.x;
    const size_t r0 = (size_t)blockIdx.x * 2;
    const float* __restrict__ xa = sino + r0 * ND;
    const float* __restrict__ xb = xa + ND;
    float* __restrict__ ya = outp + r0 * ND;
    float* __restrict__ yb = ya + ND;

    #pragma unroll
    for (int i = 0; i < ND; i += 256)
        bufA[i + tid] = make_float2(xa[i + tid], xb[i + tid]);
    #pragma unroll
    for (int i = 0; i < ND / 2; i += 256) {
        int m = i + tid;
        float ang = (float)(-2.0 * M_PI / (double)ND) * (float)m;
        float s, c;
        sincosf(ang, &s, &c);
        tw[m] = make_float2(c, s);
    }
    __syncthreads();

    float2* src = bufA;
    float2* dst = bufB;

    // forward FFT: Stockham, Ns = 1..512
    for (int Ns = 1; Ns < ND; Ns <<= 1) {
        #pragma unroll
        for (int q = 0; q < ND / 2; q += 256) {
            int j = q + tid;
            int m = j & (Ns - 1);
            float2 v0 = src[j];
            float2 v1 = src[j + ND / 2];
            float2 w = tw[m * (ND / 2 / Ns)];
            float tr = w.x * v1.x - w.y * v1.y;
            float ti = w.x * v1.y + w.y * v1.x;
            int d = ((j & ~(Ns - 1)) << 1) + m;
            dst[d]      = make_float2(v0.x + tr, v0.y + ti);
            dst[d + Ns] = make_float2(v0.x - tr, v0.y - ti);
        }
        __syncthreads();
        float2* tmp = src; src = dst; dst = tmp;
    }

    // multiply by real filter, with 1/ND folded in
    const float SCALE = 1.0f / (float)ND;
    #pragma unroll
    for (int i = 0; i < ND; i += 256) {
        float f = filt[i + tid] * SCALE;
        src[i + tid].x *= f;
        src[i + tid].y *= f;
    }
    __syncthreads();

    // inverse FFT: same flow with conjugated twiddles
    for (int Ns = 1; Ns < ND; Ns <<= 1) {
        #pragma unroll
        for (int q = 0; q < ND / 2; q += 256) {
            int j = q + tid;
            int m = j & (Ns - 1);
            float2 v0 = src[j];
            float2 v1 = src[j + ND / 2];
            float2 w = tw[m * (ND / 2 / Ns)];
            float tr = w.x * v1.x + w.y * v1.y;   // conj(w)*v1
            float ti = w.x * v1.y - w.y * v1.x;
            int d = ((j & ~(Ns - 1)) << 1) + m;
            dst[d]      = make_float2(v0.x + tr, v0.y + ti);
            dst[d + Ns] = make_float2(v0.x - tr, v0.y - ti);
        }
        __syncthreads();
        float2* tmp = src; src = dst; dst = tmp;
    }

    #pragma unroll
    for (int i = 0; i < ND; i += 256) {
        ya[i + tid] = src[i + tid].x;   // row r0   (Re)
        yb[i + tid] = src[i + tid].y;   // row r0+1 (Im)
    }
}

// ---------------------------------------------------------------------------
// Kernel 2: backprojection. 64x16 tile x 2 BATCHES per 256-thread block.
// Window entry i = 8B, BATCH-PAIRED fp16: word0 = (h(f_b0), h(f_b1)),
// word1 = (h(df_b0), h(df_b1)). One ds_read_b64 + one v_pk_add_f16 + one
// v_pk_fma_f16 serve BOTH batches' lerp-accumulates (kernel is VALU-issue
// bound; R5's fp32 unpack cost 8 inst/k, this costs 2). fp16 accumulator
// flushed to fp32 every GROUP=16 angles (group |sum| <= ~48, fp16-safe).
// Bounds check eliminated: |px*c+py*s| <= 361.3 < 511.5 always in range.
// ---------------------------------------------------------------------------
__global__ __launch_bounds__(256, 8) void backproj_kernel(const float* __restrict__ filtered,
                                                          const float2* __restrict__ cs_tab,
                                                          float* __restrict__ img) {
    __shared__ __align__(16) uint2 win[2][WINN];   // 1.5 KB

    const int tid = threadIdx.x;
    const int bx = blockIdx.x, by = blockIdx.y, bz = blockIdx.z;

    const float x0 = (float)(bx * TW) - 255.5f;
    const float x1 = x0 + (float)(TW - 1);
    const float y0 = (float)(by * TH) - 255.5f;

    // per-angle params, block-uniform: (c, s, 511.5-base, bits(a*ND+base))
    // s >= 0 for angles in [0, pi) -> min over y at y0.
    auto calc_params = [&](int a) -> float4 {
        float2 cs = cs_tab[a];           // uniform address -> scalar load
        float tmin = 511.5f + fminf(x0 * cs.x, x1 * cs.x) + y0 * cs.y;
        int base = (int)floorf(tmin) - 1;
        return make_float4(cs.x, cs.y, 511.5f - (float)base,
                           __int_as_float(a * ND + base));
    };

    // staging: threads 0..WINN-1 each build one full 8B entry (both batches)
    const bool stg = tid < WINN;
    const float* __restrict__ srow0 =
        filtered + (size_t)(bz * 2) * NA * ND + tid;
    const float* __restrict__ srow1 = srow0 + (size_t)NA * ND;

    const int tx  = tid & (TW - 1);
    const int ty0 = (tid / TW) * PXT;
    const float px  = (float)(bx * TW + tx)  - 255.5f;
    const float pyf = (float)(by * TH + ty0) - 255.5f;

    float acc0[PXT], acc1[PXT];
    __half2 hacc[PXT];
    #pragma unroll
    for (int k = 0; k < PXT; k++) {
        acc0[k] = 0.0f; acc1[k] = 0.0f; hacc[k] = u32_to_h2(0u);
    }

    // prologue: stage angle 0 into phase 0
    float4 P = calc_params(0);
    if (stg) {
        int soff = __float_as_int(P.w);
        float f0 = srow0[soff], f0n = srow0[soff + 1];
        float f1 = srow1[soff], f1n = srow1[soff + 1];
        win[0][tid] = make_uint2(pkrtz_u32(f0, f1),
                                 pkrtz_u32(f0n - f0, f1n - f1));
    }
    __syncthreads();

    for (int g = 0; g < NA; g += GROUP) {
        for (int a0 = 0; a0 < GROUP; a0 += 2) {
            #pragma unroll
            for (int p = 0; p < 2; p++) {
                const int a = g + a0 + p;
                float4 Pn = P;
                uint2 stage_val = make_uint2(0u, 0u);
                const bool pre = (a + 1 < NA);
                if (pre) {
                    Pn = calc_params(a + 1);
                    if (stg) {
                        int soff = __float_as_int(Pn.w);
                        float f0 = srow0[soff], f0n = srow0[soff + 1];
                        float f1 = srow1[soff], f1n = srow1[soff + 1];
                        stage_val = make_uint2(pkrtz_u32(f0, f1),
                                               pkrtz_u32(f0n - f0, f1n - f1));
                    }
                }

                const float sy = P.y;
                const float tb = fmaf(px, P.x, fmaf(pyf, sy, P.z));
                #pragma unroll
                for (int k = 0; k < PXT; k++) {
                    float t  = fmaf((float)k, sy, tb);
                    int   i0 = (int)t;                    // t > 0 -> trunc == floor
#if __has_builtin(__builtin_amdgcn_fractf)
                    float w  = __builtin_amdgcn_fractf(t);
#else
                    float w  = t - (float)i0;
#endif
                    __half2 wh2 = u32_to_h2(pkrtz_u32(w, w));   // one pkrtz
                    const uint2 pk = win[p][i0];                // ds_read_b64
                    hacc[k] = __hadd2(hacc[k], u32_to_h2(pk.x));          // += (f0,f1)
                    hacc[k] = __hfma2(wh2, u32_to_h2(pk.y), hacc[k]);     // += w*(df0,df1)
                }

                if (pre && stg)
                    win[p ^ 1][tid] = stage_val;
                P = Pn;
                __syncthreads();
            }
        }
        // flush fp16 group accumulator into fp32
        #pragma unroll
        for (int k = 0; k < PXT; k++) {
            float2 v = __half22float2(hacc[k]);
            acc0[k] += v.x;
            acc1[k] += v.y;
            hacc[k] = u32_to_h2(0u);
        }
    }

    const float SCALE = (float)(M_PI / (double)NA);
    size_t o0 = (((size_t)(bz * 2) * NH) + (by * TH + ty0)) * NW + (bx * TW + tx);
    size_t o1 = o0 + (size_t)NH * NW;
    #pragma unroll
    for (int k = 0; k < PXT; k++) {
        img[o0 + (size_t)k * NW] = acc0[k] * SCALE;
        img[o1 + (size_t)k * NW] = acc1[k] * SCALE;
    }
}

// ---------------------------------------------------------------------------
extern "C" void kernel_launch(void* const* d_in, const int* in_sizes, int n_in,
                              void* d_out, int out_size, void* d_ws, size_t ws_size,
                              hipStream_t stream) {
    const float* sino = (const float*)d_in[0];
    const float* filt = (const float*)d_in[1];
    float* out = (float*)d_out;

    const size_t filt_bytes = (size_t)NB * NA * ND * sizeof(float);
    float* filtered;
    float2* cs_tab;
    if (ws_size >= filt_bytes + 4096) {
        filtered = (float*)d_ws;
        cs_tab = (float2*)((char*)d_ws + filt_bytes);
    } else {
        // fallback: filter in-place into the input (harness restores inputs
        // from a pristine copy before every launch)
        filtered = (float*)d_in[0];
        cs_tab = (float2*)d_ws;
    }

    angle_kernel<<<dim3(3), dim3(256), 0, stream>>>(cs_tab);
    filter_kernel<<<dim3(NB * NA / 2), dim3(256), 0, stream>>>(sino, filt, filtered);
    backproj_kernel<<<dim3(NW / TW, NH / TH, NB / 2), dim3(256), 0, stream>>>(filtered, cs_tab, out);
}